// Round 7
// baseline (121.478 us; speedup 1.0000x reference)
//
#include <hip/hip_runtime.h>
#include <math.h>

#define B 1024
#define C 100000
#define D 64
#define MT 128                  // rows per block
#define TC 256                  // classes per block
#define NCH 391                 // ceil(C/TC); NCH*TC = 100096
#define CPAD (NCH * TC - C)     // 96 zero pad rows
#define NBLK (8 * NCH)          // 3128 blocks total (8 row-blocks x 391 ct)
#define L2E 1.4426950408889634f
#define SCL2 (2.0f * L2E)       // folded into A so exponent = MFMA acc directly

typedef __attribute__((ext_vector_type(8))) short short8;
typedef __attribute__((ext_vector_type(4))) float f32x4;

// ws byte layout: partial float [ct][row]  (1.6 MB) at offset 0.
#define GLB(p) ((const __attribute__((address_space(1))) void*)(p))
#define LDS(p) ((__attribute__((address_space(3))) void*)(p))

static __device__ __forceinline__ unsigned short f2bf(float f) {
    unsigned u = __float_as_uint(f);
    return (unsigned short)((u + 0x7fffu + ((u >> 16) & 1u)) >> 16);  // RNE
}
static __device__ __forceinline__ float bf_round(float f) {
    return __uint_as_float(((unsigned)f2bf(f)) << 16);
}
static __device__ __forceinline__ float fexp2(float x) {
#if __has_builtin(__builtin_amdgcn_exp2f)
    return __builtin_amdgcn_exp2f(x);
#else
    return __expf(x * 0.6931471805599453f);
#endif
}

// DPP permute within 16-lane rows (quad_perm / row_half_mirror / row_mirror)
#define DPPF(x, ctrl) __uint_as_float((unsigned)__builtin_amdgcn_update_dpp( \
    0, (int)__float_as_uint(x), (ctrl), 0xF, 0xF, true))

// sum over a 16-lane group; bitwise identical to shfl_xor 1,2,4,8 tree
static __device__ __forceinline__ float row16_sum(float ss) {
    ss += DPPF(ss, 0xB1);      // ^1
    ss += DPPF(ss, 0x4E);      // ^2
    ss += DPPF(ss, 0x141);     // row_half_mirror (== ^4 partner value here)
    ss += DPPF(ss, 0x140);     // row_mirror      (== ^8 partner value here)
    return ss;
}

// ---- main: fused normalize/convert staging + MFMA GEMM + exp2 epilogue ----
// XCD-affine id remap: hw XCD assignment is (hw_id % 8). We map hw id
// h = 64q + 8*rb + c  ->  ct = 8q + c, row-block = rb, so all 8 row-blocks
// sharing a ct have ids with equal residue mod 8 => SAME XCD, consecutive
// in that XCD's dispatch sequence. First one pulls the 64KB fp32 proxy
// tile to L2; the other 7 hit L2. (r5's 4x duplicated FETCH came from the
// round-robin spreading these 8 blocks across all XCDs.)
__global__ __launch_bounds__(512, 4) void proxynca_main(
    const float* __restrict__ xs, const float* __restrict__ proxies,
    float* __restrict__ partial, float* __restrict__ out)
{
    __shared__ __align__(16) unsigned short Ash[MT * 64];   // 16 KB, XOR-swizzled
    __shared__ __align__(16) unsigned short Bsh[TC * 64];   // 32 KB, XOR-swizzled
    __shared__ __align__(16) float crow[MT];                // cw2 per local row
    __shared__ float rowsum[2][4][64];                      // [mg][ng][row-in-group]

    const int h = blockIdx.x;
    int rb, ct;
    if (h < 3072) { ct = ((h >> 6) << 3) + (h & 7); rb = (h >> 3) & 7; }
    else          { int hp = h - 3072; ct = 384 + (hp >> 3); rb = hp & 7; }

    const int t = threadIdx.x;                 // 0..511
    const int lane = t & 63;
    const int wv = t >> 6;                     // 0..7
    const int row0 = rb * MT;
    const int prow = t >> 4;                   // 0..31: row-in-round for staging
    const int f4 = t & 15;                     // float4 index within a row

    if (h == 0 && t == 0) out[0] = 0.f;        // zeroed before reduce's atomics

    // Issue all staging loads up front (latency overlap; L2-hit for 7/8 blocks).
    float4 pv[8];                              // B tile: 8 rounds x 32 rows
    #pragma unroll
    for (int r = 0; r < 8; ++r) {
        int gr = ct * TC + r * 32 + prow;
        pv[r] = (gr < C) ? *(const float4*)(proxies + (size_t)gr * D + f4 * 4)
                         : make_float4(0.f, 0.f, 0.f, 0.f);
    }
    float4 xv[4];                              // A tile: 4 rounds x 32 rows
    #pragma unroll
    for (int r = 0; r < 4; ++r) {
        int gr = row0 + r * 32 + prow;
        xv[r] = *(const float4*)(xs + (size_t)gr * D + f4 * 4);
    }

    // B: L2-normalize in registers -> bf16 -> swizzled LDS write.
    // LDS chunk (row, ql) holds global chunk (row, ql ^ (row&7)) — matches the
    // fragment-read swizzle below. (Numerics identical to r5's verified pass.)
    #pragma unroll
    for (int r = 0; r < 8; ++r) {
        float4 v = pv[r];
        float ss = row16_sum(v.x*v.x + v.y*v.y + v.z*v.z + v.w*v.w);
        float rn = 1.0f / fmaxf(sqrtf(ss), 1e-12f);
        ushort4 w;
        w.x = f2bf(v.x * rn); w.y = f2bf(v.y * rn);
        w.z = f2bf(v.z * rn); w.w = f2bf(v.w * rn);
        int row = r * 32 + prow;
        *(ushort4*)(Bsh + (size_t)row * 64 + (((f4 >> 1) ^ (row & 7)) * 8) + (f4 & 1) * 4) = w;
    }
    // A: scale by 2*log2e -> bf16 -> swizzled LDS write; cw2 -> crow.
    #pragma unroll
    for (int r = 0; r < 4; ++r) {
        float4 v = xv[r];
        float ss = row16_sum(v.x*v.x + v.y*v.y + v.z*v.z + v.w*v.w);
        ushort4 w;
        w.x = f2bf(v.x * SCL2); w.y = f2bf(v.y * SCL2);
        w.z = f2bf(v.z * SCL2); w.w = f2bf(v.w * SCL2);
        int row = r * 32 + prow;
        *(ushort4*)(Ash + (size_t)row * 64 + (((f4 >> 1) ^ (row & 7)) * 8) + (f4 & 1) * 4) = w;
        if (f4 == 0) crow[row] = -2.0f * sqrtf(ss) * L2E;
    }
    __syncthreads();

    const int quad = lane >> 4, sixt = lane & 15;
    const int mg = wv >> 2, ng = wv & 3;

    // per-row C-seed constants (broadcast LDS reads, conflict-free)
    f32x4 cwv[4];
    #pragma unroll
    for (int ms = 0; ms < 4; ++ms)
        cwv[ms] = *(const f32x4*)(crow + mg * 64 + ms * 16 + quad * 4);

    short8 af[4][2];
    #pragma unroll
    for (int ms = 0; ms < 4; ++ms) {
        int rowL = mg * 64 + ms * 16 + sixt;
        int sw = rowL & 7;
        af[ms][0] = *(const short8*)(Ash + (size_t)(((rowL << 3) | (quad ^ sw)) * 8));
        af[ms][1] = *(const short8*)(Ash + (size_t)(((rowL << 3) | ((4 + quad) ^ sw)) * 8));
    }

    f32x4 s_vec[4];
    #pragma unroll
    for (int ms = 0; ms < 4; ++ms) s_vec[ms] = (f32x4){0.f, 0.f, 0.f, 0.f};

    #pragma unroll
    for (int ns = 0; ns < 4; ++ns) {
        int classL = ng * 64 + ns * 16 + sixt;
        int sw = classL & 7;
        short8 b0 = *(const short8*)(Bsh + (size_t)(((classL << 3) | (quad ^ sw)) * 8));
        short8 b1 = *(const short8*)(Bsh + (size_t)(((classL << 3) | ((4 + quad) ^ sw)) * 8));
        #pragma unroll
        for (int ms = 0; ms < 4; ++ms) {
            // acc = 2*l2e*(x.p) + cw2 directly: C-operand seeded with cw2
            f32x4 acc = __builtin_amdgcn_mfma_f32_16x16x32_bf16(af[ms][0], b0, cwv[ms], 0, 0, 0);
            acc = __builtin_amdgcn_mfma_f32_16x16x32_bf16(af[ms][1], b1, acc, 0, 0, 0);
            f32x4 e;
            #pragma unroll
            for (int rg = 0; rg < 4; ++rg) e[rg] = fexp2(acc[rg]);
            s_vec[ms] += e;
        }
    }

    // 16 values over 16 lanes: exchange-and-halve tree with DPP.
    // Mask at step k must not flip selector bits of earlier steps:
    // ^15 (sel bit3), ^7 (sel bit2), ^2 (sel bit1), ^1 (sel bit0).
    float v[16];
    #pragma unroll
    for (int ms = 0; ms < 4; ++ms)
        #pragma unroll
        for (int rg = 0; rg < 4; ++rg) v[ms * 4 + rg] = s_vec[ms][rg];

    {   bool b = (sixt & 8) != 0;               // row_mirror = ^15
        #pragma unroll
        for (int j = 0; j < 8; ++j) {
            float k = b ? v[j + 8] : v[j];
            float s = b ? v[j] : v[j + 8];
            v[j] = k + DPPF(s, 0x140);
        }
    }
    {   bool b = (sixt & 4) != 0;               // row_half_mirror = ^7
        #pragma unroll
        for (int j = 0; j < 4; ++j) {
            float k = b ? v[j + 4] : v[j];
            float s = b ? v[j] : v[j + 4];
            v[j] = k + DPPF(s, 0x141);
        }
    }
    {   bool b = (sixt & 2) != 0;               // quad_perm [2,3,0,1] = ^2
        #pragma unroll
        for (int j = 0; j < 2; ++j) {
            float k = b ? v[j + 2] : v[j];
            float s = b ? v[j] : v[j + 2];
            v[j] = k + DPPF(s, 0x4E);
        }
    }
    {   bool b = (sixt & 1) != 0;               // quad_perm [1,0,3,2] = ^1
        float k = b ? v[1] : v[0];
        float s = b ? v[0] : v[1];
        v[0] = k + DPPF(s, 0xB1);
    }

    // lane holds total for local row lrow = (sixt>>2)*16 + quad*4 + (sixt&3).
    // Stage per-ng sums in LDS, then ng==0 waves combine 4 ng's and emit one
    // coalesced 256B line per (mg, ct).
    int lrow = ((sixt >> 2) << 4) + (quad << 2) + (sixt & 3);
    rowsum[mg][ng][lrow] = v[0];
    __syncthreads();
    if (ng == 0) {
        float r = rowsum[mg][0][lane] + rowsum[mg][1][lane]
                + rowsum[mg][2][lane] + rowsum[mg][3][lane];
        partial[(size_t)ct * B + row0 + mg * 64 + lane] = r;
    }
}

// ---- reduce + final mean (atomicAdd into out, zeroed by main block 0) ----
__global__ __launch_bounds__(256) void proxynca_reduce(
    const float* __restrict__ xs, const int* __restrict__ ys,
    const float* __restrict__ proxies, const float* __restrict__ partial,
    float* __restrict__ out)
{
    __shared__ float acc4[4];
    const int lane = threadIdx.x & 63;
    const int w = threadIdx.x >> 6;
    const int row = blockIdx.x * 4 + w;

    float x = xs[(size_t)row * D + lane];
    int y = ys[row];
    float p = proxies[(size_t)y * D + lane];

    float xx = x * x, pp = p * p;
    #pragma unroll
    for (int off = 1; off < 64; off <<= 1) {
        xx += __shfl_xor(xx, off);
        pp += __shfl_xor(pp, off);
    }
    float nx = sqrtf(xx);
    float rn = 1.0f / fmaxf(sqrtf(pp), 1e-12f);
    float ph = p * rn;

    float xp = x * ph;                             // exact fp32 dot for d_pos
    float xpb = bf_round(x * SCL2) * bf_round(ph); // bf16-matched (scaled) dot
    #pragma unroll
    for (int off = 1; off < 64; off <<= 1) {
        xp  += __shfl_xor(xp, off);
        xpb += __shfl_xor(xpb, off);
    }

    float s = 0.f;
    for (int ct = lane; ct < NCH; ct += 64) s += partial[(size_t)ct * B + row];
    #pragma unroll
    for (int off = 1; off < 64; off <<= 1) s += __shfl_xor(s, off);

    if (lane == 0) {
        float cw2r = -2.0f * nx * L2E;
        float e_pos = fexp2(xpb + cw2r);            // matches main's C-init form
        float e_pad = fexp2(cw2r);                  // each zero pad row
        float s_neg = s - e_pos - (float)CPAD * e_pad;
        acc4[w] = 2.0f * (nx - xp) + logf(s_neg);
    }
    __syncthreads();
    if (threadIdx.x == 0) {
        float v = acc4[0] + acc4[1] + acc4[2] + acc4[3];
        atomicAdd(out, v * (1.0f / (float)B));
    }
}

extern "C" void kernel_launch(void* const* d_in, const int* in_sizes, int n_in,
                              void* d_out, int out_size, void* d_ws, size_t ws_size,
                              hipStream_t stream)
{
    const float* xs      = (const float*)d_in[0];
    const int*   ys      = (const int*)d_in[1];
    const float* proxies = (const float*)d_in[2];
    float* partial = (float*)d_ws;
    float* out = (float*)d_out;

    proxynca_main<<<NBLK, 512, 0, stream>>>(xs, proxies, partial, out);
    proxynca_reduce<<<B / 4, 256, 0, stream>>>(xs, ys, proxies, partial, out);
}

// Round 8
// 106.497 us; speedup vs baseline: 1.1407x; 1.1407x over previous
//
#include <hip/hip_runtime.h>
#include <math.h>

#define B 1024
#define C 100000
#define D 64
#define MT 128                  // rows per block
#define TC 256                  // classes per block
#define NCH 391                 // ceil(C/TC); NCH*TC = 100096
#define NPADROWS (NCH * TC)     // 100096
#define CPAD (NPADROWS - C)     // 96 zero pad rows
#define NBLK (8 * NCH)          // 3128 blocks (8 row-blocks x 391 ct)
#define L2E 1.4426950408889634f
#define SCL2 (2.0f * L2E)       // folded into Xbf so exponent = MFMA acc directly

typedef __attribute__((ext_vector_type(8))) short short8;
typedef __attribute__((ext_vector_type(4))) float f32x4;

// ws byte layout (total ~14.6 MB):
//   [0, NCH*B*4)        : partial float [ct][row]  (1.6 MB, ng-combined)
//   WS_CW2  (+4KB)      : cw2[row] = -2*||x_row||*log2e
//   WS_XBF  (+128KB)    : xs*2*log2e as bf16 [B][64]
//   WS_PBF  (+12.8MB)   : normalized proxies as bf16 [NPADROWS][64] (pad rows 0)
#define WS_PART 0
#define WS_CW2  ((size_t)NCH * B * 4)
#define WS_XBF  (WS_CW2 + B * 4)
#define WS_PBF  (WS_XBF + (size_t)B * D * 2)

#define GLB(p) ((const __attribute__((address_space(1))) void*)(p))
#define LDS(p) ((__attribute__((address_space(3))) void*)(p))

static __device__ __forceinline__ unsigned short f2bf(float f) {
    unsigned u = __float_as_uint(f);
    return (unsigned short)((u + 0x7fffu + ((u >> 16) & 1u)) >> 16);  // RNE
}
static __device__ __forceinline__ float bf_round(float f) {
    return __uint_as_float(((unsigned)f2bf(f)) << 16);
}
static __device__ __forceinline__ float fexp2(float x) {
#if __has_builtin(__builtin_amdgcn_exp2f)
    return __builtin_amdgcn_exp2f(x);
#else
    return __expf(x * 0.6931471805599453f);
#endif
}

// DPP permute within 16-lane rows (quad_perm / row_half_mirror / row_mirror)
#define DPPF(x, ctrl) __uint_as_float((unsigned)__builtin_amdgcn_update_dpp( \
    0, (int)__float_as_uint(x), (ctrl), 0xF, 0xF, true))

// ---- prep: normalize proxies -> bf16 (pad rows zero); xs*2L2E -> bf16; cw2;
//      also zeroes the scalar output (replaces a memset dispatch) ----
__global__ __launch_bounds__(256) void proxynca_prep(
    const float* __restrict__ xs, const float* __restrict__ proxies,
    unsigned short* __restrict__ Xbf, unsigned short* __restrict__ Pbf,
    float* __restrict__ cw2, float* __restrict__ out)
{
    const int t = threadIdx.x;
    const int rl = t >> 4, f4 = t & 15;         // 16 lanes per row
    const int bb = blockIdx.x;
    if (bb == 0 && t == 0) out[0] = 0.f;        // zero out before reduce's atomics
    if (bb < NPADROWS / 16) {
        int gr = bb * 16 + rl;
        float4 v = make_float4(0.f, 0.f, 0.f, 0.f);
        if (gr < C) v = *(const float4*)(proxies + (size_t)gr * D + f4 * 4);
        float ss = v.x*v.x + v.y*v.y + v.z*v.z + v.w*v.w;
        ss += __shfl_xor(ss, 1); ss += __shfl_xor(ss, 2);
        ss += __shfl_xor(ss, 4); ss += __shfl_xor(ss, 8);
        float rn = 1.0f / fmaxf(sqrtf(ss), 1e-12f);
        ushort4 w;
        w.x = f2bf(v.x * rn); w.y = f2bf(v.y * rn);
        w.z = f2bf(v.z * rn); w.w = f2bf(v.w * rn);
        *(ushort4*)(Pbf + (size_t)gr * D + f4 * 4) = w;
    } else {
        int row = (bb - NPADROWS / 16) * 16 + rl;   // 0..1023
        float4 v = *(const float4*)(xs + (size_t)row * D + f4 * 4);
        float ss = v.x*v.x + v.y*v.y + v.z*v.z + v.w*v.w;
        ss += __shfl_xor(ss, 1); ss += __shfl_xor(ss, 2);
        ss += __shfl_xor(ss, 4); ss += __shfl_xor(ss, 8);
        ushort4 w;                                   // pre-scaled by 2*log2e
        w.x = f2bf(v.x * SCL2); w.y = f2bf(v.y * SCL2);
        w.z = f2bf(v.z * SCL2); w.w = f2bf(v.w * SCL2);
        *(ushort4*)(Xbf + (size_t)row * D + f4 * 4) = w;
        if (f4 == 0) cw2[row] = -2.0f * sqrtf(ss) * L2E;
    }
}

// ---- main: MFMA GEMM tile (C-init = cw2) + fused exp2 epilogue ----
// XCD-affine 1D remap (verified in r7: bijective, absmax 0.0, FETCH 7x lower):
// h = 64q + 8*rb + c -> ct = 8q + c, row-block = rb. XCD = h % 8 = c, so the
// 8 row-blocks sharing a ct land CONSECUTIVELY on ONE XCD: its L2 fills the
// 32KB Pbf tile once, 7 blocks hit. (Old 2D grid: xcd=rb => 8x duplicated
// L2 fills of every Pbf tile, ~100MB/iter through the L3 fabric.)
__global__ __launch_bounds__(512, 4) void proxynca_main(
    const unsigned short* __restrict__ Xbf, const unsigned short* __restrict__ Pbf,
    const float* __restrict__ cw2v, float* __restrict__ partial)
{
    __shared__ __align__(16) unsigned short Ash[MT * 64];   // 16 KB, XOR-swizzled
    __shared__ __align__(16) unsigned short Bsh[TC * 64];   // 32 KB, XOR-swizzled
    __shared__ float rowsum[2][4][64];                      // [mg][ng][row-in-group]

    const int h = blockIdx.x;
    int rb, ct;
    if (h < 3072) { ct = ((h >> 6) << 3) + (h & 7); rb = (h >> 3) & 7; }
    else          { int hp = h - 3072; ct = 384 + (hp >> 3); rb = hp & 7; }

    const int t = threadIdx.x;                 // 0..511
    const int lane = t & 63;
    const int wv = t >> 6;                     // 0..7
    const int row0 = rb * MT;

    const unsigned short* Asrc = Xbf + (size_t)row0 * D;
    const unsigned short* Bsrc = Pbf + (size_t)ct * TC * D;

    // A tile: 1024 16B-chunks, 2 rounds; source index XOR-swizzled so LDS
    // chunk (row, q) holds global chunk (row, q ^ (row&7)) (involution).
    #pragma unroll
    for (int j = 0; j < 2; ++j) {
        int c = (j * 8 + wv) * 64 + lane;
        int row = c >> 3, q = c & 7;
        int sc = (row << 3) | (q ^ (row & 7));
        __builtin_amdgcn_global_load_lds(GLB(Asrc + sc * 8),
            LDS(Ash + (size_t)(j * 8 + wv) * 512), 16, 0, 0);
    }
    // B tile: 2048 chunks, 4 rounds
    #pragma unroll
    for (int j = 0; j < 4; ++j) {
        int c = (j * 8 + wv) * 64 + lane;
        int row = c >> 3, q = c & 7;
        int sc = (row << 3) | (q ^ (row & 7));
        __builtin_amdgcn_global_load_lds(GLB(Bsrc + sc * 8),
            LDS(Bsh + (size_t)(j * 8 + wv) * 512), 16, 0, 0);
    }

    const int quad = lane >> 4, sixt = lane & 15;
    const int mg = wv >> 2, ng = wv & 3;

    // per-row constants, loaded while tile loads are in flight (L2 hits)
    f32x4 cwv[4];
    #pragma unroll
    for (int ms = 0; ms < 4; ++ms)
        cwv[ms] = *(const f32x4*)(cw2v + row0 + mg * 64 + ms * 16 + quad * 4);

    __syncthreads();

    short8 af[4][2];
    #pragma unroll
    for (int ms = 0; ms < 4; ++ms) {
        int rowL = mg * 64 + ms * 16 + sixt;
        int sw = rowL & 7;
        af[ms][0] = *(const short8*)(Ash + (size_t)(((rowL << 3) | (quad ^ sw)) * 8));
        af[ms][1] = *(const short8*)(Ash + (size_t)(((rowL << 3) | ((4 + quad) ^ sw)) * 8));
    }

    f32x4 s_vec[4];
    #pragma unroll
    for (int ms = 0; ms < 4; ++ms) s_vec[ms] = (f32x4){0.f, 0.f, 0.f, 0.f};

    #pragma unroll
    for (int ns = 0; ns < 4; ++ns) {
        int classL = ng * 64 + ns * 16 + sixt;
        int sw = classL & 7;
        short8 b0 = *(const short8*)(Bsh + (size_t)(((classL << 3) | (quad ^ sw)) * 8));
        short8 b1 = *(const short8*)(Bsh + (size_t)(((classL << 3) | ((4 + quad) ^ sw)) * 8));
        #pragma unroll
        for (int ms = 0; ms < 4; ++ms) {
            // acc = 2*l2e*(x.p) + cw2 directly: C-operand seeded with cw2
            f32x4 acc = __builtin_amdgcn_mfma_f32_16x16x32_bf16(af[ms][0], b0, cwv[ms], 0, 0, 0);
            acc = __builtin_amdgcn_mfma_f32_16x16x32_bf16(af[ms][1], b1, acc, 0, 0, 0);
            f32x4 e;
            #pragma unroll
            for (int rg = 0; rg < 4; ++rg) e[rg] = fexp2(acc[rg]);
            s_vec[ms] += e;
        }
    }

    // 16 values over 16 lanes: exchange-and-halve tree with DPP.
    // Mask at step k must not flip selector bits of earlier steps, so the
    // order is forced: ^15 (sel bit3), ^7 (sel bit2), ^2 (sel bit1), ^1 (sel bit0).
    // Final: lane sixt holds the 16-lane total for index idx == sixt.
    float v[16];
    #pragma unroll
    for (int ms = 0; ms < 4; ++ms)
        #pragma unroll
        for (int rg = 0; rg < 4; ++rg) v[ms * 4 + rg] = s_vec[ms][rg];

    {   bool b = (sixt & 8) != 0;               // row_mirror = ^15
        #pragma unroll
        for (int j = 0; j < 8; ++j) {
            float k = b ? v[j + 8] : v[j];
            float s = b ? v[j] : v[j + 8];
            v[j] = k + DPPF(s, 0x140);
        }
    }
    {   bool b = (sixt & 4) != 0;               // row_half_mirror = ^7
        #pragma unroll
        for (int j = 0; j < 4; ++j) {
            float k = b ? v[j + 4] : v[j];
            float s = b ? v[j] : v[j + 4];
            v[j] = k + DPPF(s, 0x141);
        }
    }
    {   bool b = (sixt & 2) != 0;               // quad_perm [2,3,0,1] = ^2
        #pragma unroll
        for (int j = 0; j < 2; ++j) {
            float k = b ? v[j + 2] : v[j];
            float s = b ? v[j] : v[j + 2];
            v[j] = k + DPPF(s, 0x4E);
        }
    }
    {   bool b = (sixt & 1) != 0;               // quad_perm [1,0,3,2] = ^1
        float k = b ? v[1] : v[0];
        float s = b ? v[0] : v[1];
        v[0] = k + DPPF(s, 0xB1);
    }

    // lane holds total for local row lrow = (sixt>>2)*16 + quad*4 + (sixt&3).
    // Stage per-ng sums in LDS (indexed by lrow: 2 lanes/bank, conflict-free),
    // then ng==0 waves combine 4 ng's and emit one coalesced 256B line.
    int lrow = ((sixt >> 2) << 4) + (quad << 2) + (sixt & 3);
    rowsum[mg][ng][lrow] = v[0];
    __syncthreads();
    if (ng == 0) {
        float r = rowsum[mg][0][lane] + rowsum[mg][1][lane]
                + rowsum[mg][2][lane] + rowsum[mg][3][lane];
        partial[(size_t)ct * B + row0 + mg * 64 + lane] = r;
    }
}

// ---- reduce + final mean (atomicAdd into out, zeroed by prep) ----
__global__ __launch_bounds__(256) void proxynca_reduce(
    const float* __restrict__ xs, const int* __restrict__ ys,
    const float* __restrict__ proxies, const float* __restrict__ partial,
    float* __restrict__ out)
{
    __shared__ float acc4[4];
    const int lane = threadIdx.x & 63;
    const int w = threadIdx.x >> 6;
    const int row = blockIdx.x * 4 + w;

    float x = xs[(size_t)row * D + lane];
    int y = ys[row];
    float p = proxies[(size_t)y * D + lane];

    float xx = x * x, pp = p * p;
    #pragma unroll
    for (int off = 1; off < 64; off <<= 1) {
        xx += __shfl_xor(xx, off);
        pp += __shfl_xor(pp, off);
    }
    float nx = sqrtf(xx);
    float rn = 1.0f / fmaxf(sqrtf(pp), 1e-12f);
    float ph = p * rn;

    float xp = x * ph;                             // exact fp32 dot for d_pos
    float xpb = bf_round(x * SCL2) * bf_round(ph); // bf16-matched (scaled) dot
    #pragma unroll
    for (int off = 1; off < 64; off <<= 1) {
        xp  += __shfl_xor(xp, off);
        xpb += __shfl_xor(xpb, off);
    }

    float s = 0.f;
    for (int ct = lane; ct < NCH; ct += 64) s += partial[(size_t)ct * B + row];
    #pragma unroll
    for (int off = 1; off < 64; off <<= 1) s += __shfl_xor(s, off);

    if (lane == 0) {
        float cw2r = -2.0f * nx * L2E;
        float e_pos = fexp2(xpb + cw2r);            // matches main's C-init form
        float e_pad = fexp2(cw2r);                  // each zero pad row
        float s_neg = s - e_pos - (float)CPAD * e_pad;
        acc4[w] = 2.0f * (nx - xp) + logf(s_neg);
    }
    __syncthreads();
    if (threadIdx.x == 0) {
        float v = acc4[0] + acc4[1] + acc4[2] + acc4[3];
        atomicAdd(out, v * (1.0f / (float)B));
    }
}

extern "C" void kernel_launch(void* const* d_in, const int* in_sizes, int n_in,
                              void* d_out, int out_size, void* d_ws, size_t ws_size,
                              hipStream_t stream)
{
    const float* xs      = (const float*)d_in[0];
    const int*   ys      = (const int*)d_in[1];
    const float* proxies = (const float*)d_in[2];
    char* ws = (char*)d_ws;
    float* partial = (float*)(ws + WS_PART);
    float* cw2     = (float*)(ws + WS_CW2);
    unsigned short* Xbf = (unsigned short*)(ws + WS_XBF);
    unsigned short* Pbf = (unsigned short*)(ws + WS_PBF);
    float* out = (float*)d_out;

    proxynca_prep<<<NPADROWS / 16 + B / 16, 256, 0, stream>>>(xs, proxies, Xbf, Pbf, cw2, out);
    proxynca_main<<<NBLK, 512, 0, stream>>>(Xbf, Pbf, cw2, partial);
    proxynca_reduce<<<B / 4, 256, 0, stream>>>(xs, ys, proxies, partial, out);
}